// Round 1
// baseline (474.151 us; speedup 1.0000x reference)
//
#include <hip/hip_runtime.h>
#include <hip/hip_bf16.h>
#include <stdint.h>

typedef __attribute__((ext_vector_type(8))) __bf16 bf16x8;
typedef __attribute__((ext_vector_type(4))) float f32x4;

#define MFMA16(a, b, c) __builtin_amdgcn_mfma_f32_16x16x32_bf16((a), (b), (c), 0, 0, 0)

__device__ __forceinline__ unsigned short f32_to_bf16_rne(float f) {
  union { float f; uint32_t u; } v; v.f = f;
  uint32_t u = v.u;
  u += 0x7fffu + ((u >> 16) & 1u);
  return (unsigned short)(u >> 16);
}

// global -> LDS direct copy, 16B per lane. LDS dest must be wave-uniform base;
// HW writes lane l at base + l*16. Global src is per-lane.
__device__ __forceinline__ void gl_lds16(const void* g, void* l) {
  __builtin_amdgcn_global_load_lds(
      (const __attribute__((address_space(1))) void*)(uintptr_t)g,
      (__attribute__((address_space(3))) void*)(uintptr_t)l,
      16, 0, 0);
}

// ---------------------------------------------------------------- cast kernel
__global__ void cast_f32_bf16_kernel(const float* __restrict__ in,
                                     unsigned short* __restrict__ out, int n4) {
  int i = blockIdx.x * blockDim.x + threadIdx.x;
  if (i >= n4) return;
  float4 v = reinterpret_cast<const float4*>(in)[i];
  ushort4 o;
  o.x = f32_to_bf16_rne(v.x);
  o.y = f32_to_bf16_rne(v.y);
  o.z = f32_to_bf16_rne(v.z);
  o.w = f32_to_bf16_rne(v.w);
  reinterpret_cast<ushort4*>(out)[i] = o;
}

// ---------------------------------------------------------------- GEMM (B^T)
// C[m,n] = sum_k A[m,k] * Bt[n,k];  A:[M,K] bf16 row-major, Bt:[N,K] bf16 row-major
// FINAL=0: C bf16.  FINAL=1: C f32 with bias add.
// 128x128 tile, BK=32, 256 threads = 4 waves (2x2), each wave 64x64 (4x4 frags).
template <int FINAL>
__global__ __launch_bounds__(256, 2) void gemm_bt_kernel(
    const unsigned short* __restrict__ A, const unsigned short* __restrict__ Bt,
    void* __restrict__ Cout, const float* __restrict__ bias, int M, int N, int K) {
  __shared__ __attribute__((aligned(16))) unsigned short As[128 * 32];
  __shared__ __attribute__((aligned(16))) unsigned short Bs[128 * 32];
  const int tid = threadIdx.x;
  const int lane = tid & 63;
  const int wid = tid >> 6;
  const int wr = wid >> 1, wc = wid & 1;
  const int m0 = blockIdx.y * 128, n0 = blockIdx.x * 128;

  f32x4 acc[4][4] = {};

  // staging: tile is [128][32] bf16 = 8KB = 8 chunks of 1KB (16 rows each).
  // chunk c -> LDS base + c*1024; lane l covers (row = c*16 + l/4, col = (l&3)*8)
  const int srow = lane >> 2;
  const int scol = (lane & 3) * 8;

  for (int k0 = 0; k0 < K; k0 += 32) {
    __syncthreads();
#pragma unroll
    for (int i = 0; i < 2; ++i) {
      const int c = wid * 2 + i;
      const int row = c * 16 + srow;
      gl_lds16(A + (size_t)(m0 + row) * K + k0 + scol, (char*)As + c * 1024);
      gl_lds16(Bt + (size_t)(n0 + row) * K + k0 + scol, (char*)Bs + c * 1024);
    }
    __syncthreads();

    bf16x8 af[4], bf[4];
#pragma unroll
    for (int mi = 0; mi < 4; ++mi)
      af[mi] = *reinterpret_cast<const bf16x8*>(
          &As[(wr * 64 + mi * 16 + (lane & 15)) * 32 + (lane >> 4) * 8]);
#pragma unroll
    for (int ni = 0; ni < 4; ++ni)
      bf[ni] = *reinterpret_cast<const bf16x8*>(
          &Bs[(wc * 64 + ni * 16 + (lane & 15)) * 32 + (lane >> 4) * 8]);
#pragma unroll
    for (int mi = 0; mi < 4; ++mi)
#pragma unroll
      for (int ni = 0; ni < 4; ++ni)
        acc[mi][ni] = MFMA16(af[mi], bf[ni], acc[mi][ni]);
  }

#pragma unroll
  for (int mi = 0; mi < 4; ++mi) {
#pragma unroll
    for (int ni = 0; ni < 4; ++ni) {
      const int row = m0 + wr * 64 + mi * 16 + ((lane >> 4) << 2);
      const int col = n0 + wc * 64 + ni * 16 + (lane & 15);
#pragma unroll
      for (int j = 0; j < 4; ++j) {
        if (FINAL) {
          reinterpret_cast<float*>(Cout)[(size_t)(row + j) * N + col] =
              acc[mi][ni][j] + bias[col];
        } else {
          reinterpret_cast<unsigned short*>(Cout)[(size_t)(row + j) * N + col] =
              f32_to_bf16_rne(acc[mi][ni][j]);
        }
      }
    }
  }
}

// ---------------------------------------------------------------- attention
// scores[t,s] = (k_t . q_s) * 0.125, causal s<=t, softmax over s, out = P @ V.
// One block per (b, h, 128-row t-tile). 4 waves, wave w owns rows w*32..w*32+31.
// s-tiles of 64. K/Q/V/attn-out live in [B*T, 1024] bf16 buffers, col = h*64+d.
__global__ __launch_bounds__(256, 2) void attn_kernel(
    const unsigned short* __restrict__ Kb, const unsigned short* __restrict__ Qb,
    const unsigned short* __restrict__ Vb, unsigned short* __restrict__ Ob) {
  const int ttile = blockIdx.x, h = blockIdx.y, b = blockIdx.z;
  const int t0 = ttile * 128;
  const int tid = threadIdx.x;
  const int lane = tid & 63;
  const int w = tid >> 6;

  __shared__ __attribute__((aligned(16))) unsigned short Ks[128 * 64];  // [t][d]
  __shared__ __attribute__((aligned(16))) unsigned short Qs[64 * 64];   // [s][d]
  __shared__ __attribute__((aligned(16))) unsigned short Vt[64 * 64];   // [d][s]
  __shared__ __attribute__((aligned(16))) unsigned short Ps[128 * 64];  // [t][s]

  const size_t base_bt = (size_t)b * 2048;

  // stage K tile: 128 rows x 128B = 16 chunks of 1KB (8 rows each)
  {
    const int r = lane >> 3;
    const int cc = (lane & 7) * 8;
#pragma unroll
    for (int i = 0; i < 4; ++i) {
      const int c = w * 4 + i;
      const int row = c * 8 + r;
      gl_lds16(Kb + (base_bt + t0 + row) * 1024 + h * 64 + cc, (char*)Ks + c * 1024);
    }
  }

  f32x4 o_acc[2][4] = {};
  float m_run[2][4], l_run[2][4];
#pragma unroll
  for (int mi = 0; mi < 2; ++mi)
#pragma unroll
    for (int j = 0; j < 4; ++j) {
      m_run[mi][j] = -1e30f;
      l_run[mi][j] = 0.f;
    }

  const int nst = t0 / 64 + 2;  // s-tiles covering s <= t0+127
  for (int st = 0; st < nst; ++st) {
    const int s0 = st * 64;
    __syncthreads();  // prev iter's reads of Qs/Vt done (also drains K staging)
    // stage Q tile: 8 chunks of 1KB
    {
      const int r = lane >> 3;
      const int cc = (lane & 7) * 8;
#pragma unroll
      for (int i = 0; i < 2; ++i) {
        const int c = w * 2 + i;
        const int row = c * 8 + r;
        gl_lds16(Qb + (base_bt + s0 + row) * 1024 + h * 64 + cc, (char*)Qs + c * 1024);
      }
    }
    // stage V transposed: Vt[d][s]
    {
#pragma unroll
      for (int it = 0; it < 2; ++it) {
        const int idx = it * 256 + tid;
        const int s = idx >> 3;
        const int d0 = (idx & 7) * 8;
        uint4 v = *reinterpret_cast<const uint4*>(
            Vb + (base_bt + s0 + s) * 1024 + h * 64 + d0);
        const unsigned short* pv = reinterpret_cast<const unsigned short*>(&v);
#pragma unroll
        for (int u = 0; u < 8; ++u) Vt[(d0 + u) * 64 + s] = pv[u];
      }
    }
    __syncthreads();

    // S = K . Q^T : per wave 32 rows x 64 cols, d = 64 (2 MFMA k-steps)
    f32x4 s_acc[2][4] = {};
#pragma unroll
    for (int kk = 0; kk < 2; ++kk) {
      bf16x8 af[2], bq[4];
#pragma unroll
      for (int mi = 0; mi < 2; ++mi)
        af[mi] = *reinterpret_cast<const bf16x8*>(
            &Ks[(w * 32 + mi * 16 + (lane & 15)) * 64 + kk * 32 + (lane >> 4) * 8]);
#pragma unroll
      for (int ni = 0; ni < 4; ++ni)
        bq[ni] = *reinterpret_cast<const bf16x8*>(
            &Qs[(ni * 16 + (lane & 15)) * 64 + kk * 32 + (lane >> 4) * 8]);
#pragma unroll
      for (int mi = 0; mi < 2; ++mi)
#pragma unroll
        for (int ni = 0; ni < 4; ++ni)
          s_acc[mi][ni] = MFMA16(af[mi], bq[ni], s_acc[mi][ni]);
    }

    // scale + causal mask. row(t) = t0 + w*32 + mi*16 + (lane>>4)*4 + j ; col(s) = s0 + ni*16 + (lane&15)
    const int colb = s0 + (lane & 15);
    const int rowb = t0 + w * 32 + ((lane >> 4) << 2);
#pragma unroll
    for (int mi = 0; mi < 2; ++mi)
#pragma unroll
      for (int ni = 0; ni < 4; ++ni) {
        const int s = colb + ni * 16;
#pragma unroll
        for (int j = 0; j < 4; ++j) {
          const int t = rowb + mi * 16 + j;
          const float vv = s_acc[mi][ni][j] * 0.125f;
          s_acc[mi][ni][j] = (s <= t) ? vv : -1e30f;
        }
      }

    // online softmax per row (rows live in 16-lane quarter groups)
#pragma unroll
    for (int mi = 0; mi < 2; ++mi) {
#pragma unroll
      for (int j = 0; j < 4; ++j) {
        float tm = fmaxf(fmaxf(s_acc[mi][0][j], s_acc[mi][1][j]),
                         fmaxf(s_acc[mi][2][j], s_acc[mi][3][j]));
        tm = fmaxf(tm, __shfl_xor(tm, 1));
        tm = fmaxf(tm, __shfl_xor(tm, 2));
        tm = fmaxf(tm, __shfl_xor(tm, 4));
        tm = fmaxf(tm, __shfl_xor(tm, 8));
        const float newm = fmaxf(m_run[mi][j], tm);
        const float alpha = __expf(m_run[mi][j] - newm);
        float rs = 0.f;
#pragma unroll
        for (int ni = 0; ni < 4; ++ni) {
          const float p = __expf(s_acc[mi][ni][j] - newm);
          s_acc[mi][ni][j] = p;
          rs += p;
        }
        rs += __shfl_xor(rs, 1);
        rs += __shfl_xor(rs, 2);
        rs += __shfl_xor(rs, 4);
        rs += __shfl_xor(rs, 8);
        l_run[mi][j] = l_run[mi][j] * alpha + rs;
        m_run[mi][j] = newm;
#pragma unroll
        for (int db = 0; db < 4; ++db) o_acc[mi][db][j] *= alpha;
      }
    }

    // P -> LDS (bf16), rows are wave-private so only wave-local ordering needed
#pragma unroll
    for (int mi = 0; mi < 2; ++mi)
#pragma unroll
      for (int ni = 0; ni < 4; ++ni)
#pragma unroll
        for (int j = 0; j < 4; ++j)
          Ps[(w * 32 + mi * 16 + ((lane >> 4) << 2) + j) * 64 + ni * 16 + (lane & 15)] =
              f32_to_bf16_rne(s_acc[mi][ni][j]);
    __syncthreads();

    // O += P @ V : A = Ps rows(t) x k(s), B[k=s][col=d] = Vt[d][s]
#pragma unroll
    for (int kk = 0; kk < 2; ++kk) {
      bf16x8 pa[2], bv[4];
#pragma unroll
      for (int mi = 0; mi < 2; ++mi)
        pa[mi] = *reinterpret_cast<const bf16x8*>(
            &Ps[(w * 32 + mi * 16 + (lane & 15)) * 64 + kk * 32 + (lane >> 4) * 8]);
#pragma unroll
      for (int db = 0; db < 4; ++db)
        bv[db] = *reinterpret_cast<const bf16x8*>(
            &Vt[(db * 16 + (lane & 15)) * 64 + kk * 32 + (lane >> 4) * 8]);
#pragma unroll
      for (int mi = 0; mi < 2; ++mi)
#pragma unroll
        for (int db = 0; db < 4; ++db)
          o_acc[mi][db] = MFMA16(pa[mi], bv[db], o_acc[mi][db]);
    }
  }

  // epilogue: normalize and store
#pragma unroll
  for (int mi = 0; mi < 2; ++mi)
#pragma unroll
    for (int db = 0; db < 4; ++db) {
      const int trow = t0 + w * 32 + mi * 16 + ((lane >> 4) << 2);
      const int col = h * 64 + db * 16 + (lane & 15);
#pragma unroll
      for (int j = 0; j < 4; ++j) {
        const float o = o_acc[mi][db][j] / l_run[mi][j];
        Ob[(base_bt + trow + j) * 1024 + col] = f32_to_bf16_rne(o);
      }
    }
}

// ---------------------------------------------------------------- launch
extern "C" void kernel_launch(void* const* d_in, const int* in_sizes, int n_in,
                              void* d_out, int out_size, void* d_ws, size_t ws_size,
                              hipStream_t stream) {
  (void)in_sizes; (void)n_in; (void)out_size; (void)ws_size;
  const float* x  = (const float*)d_in[0];
  const float* Wk = (const float*)d_in[1];
  const float* Wq = (const float*)d_in[2];
  const float* Wv = (const float*)d_in[3];
  const float* Wo = (const float*)d_in[4];
  const float* bo = (const float*)d_in[5];
  float* out = (float*)d_out;

  const int BT = 8192, E = 1024;

  char* ws = (char*)d_ws;
  unsigned short* xb  = (unsigned short*)(ws);                        // 16MB, reused as attn-out
  unsigned short* Kb  = (unsigned short*)(ws + ((size_t)16 << 20));   // 16MB
  unsigned short* Qb  = (unsigned short*)(ws + ((size_t)32 << 20));   // 16MB
  unsigned short* Vb  = (unsigned short*)(ws + ((size_t)48 << 20));   // 16MB
  unsigned short* Wkb = (unsigned short*)(ws + ((size_t)64 << 20));   // 2MB
  unsigned short* Wqb = (unsigned short*)(ws + ((size_t)66 << 20));   // 2MB
  unsigned short* Wvb = (unsigned short*)(ws + ((size_t)68 << 20));   // 2MB
  unsigned short* Wob = (unsigned short*)(ws + ((size_t)70 << 20));   // 2MB -> 72MB total

  // casts to bf16
  cast_f32_bf16_kernel<<<dim3(BT * E / 4 / 256), 256, 0, stream>>>(x, xb, BT * E / 4);
  cast_f32_bf16_kernel<<<dim3(E * E / 4 / 256), 256, 0, stream>>>(Wk, Wkb, E * E / 4);
  cast_f32_bf16_kernel<<<dim3(E * E / 4 / 256), 256, 0, stream>>>(Wq, Wqb, E * E / 4);
  cast_f32_bf16_kernel<<<dim3(E * E / 4 / 256), 256, 0, stream>>>(Wv, Wvb, E * E / 4);
  cast_f32_bf16_kernel<<<dim3(E * E / 4 / 256), 256, 0, stream>>>(Wo, Wob, E * E / 4);

  // projections: [8192,1024] = [8192,1024] x [1024,1024]^T
  dim3 gg(E / 128, BT / 128);
  gemm_bt_kernel<0><<<gg, 256, 0, stream>>>(xb, Wkb, Kb, nullptr, BT, E, E);
  gemm_bt_kernel<0><<<gg, 256, 0, stream>>>(xb, Wqb, Qb, nullptr, BT, E, E);
  gemm_bt_kernel<0><<<gg, 256, 0, stream>>>(xb, Wvb, Vb, nullptr, BT, E, E);

  // attention (writes attn output into xb; x is no longer needed)
  attn_kernel<<<dim3(16, 16, 4), 256, 0, stream>>>(Kb, Qb, Vb, xb);

  // final projection + bias, f32 out
  gemm_bt_kernel<1><<<gg, 256, 0, stream>>>(xb, Wob, out, bo, BT, E, E);
}

// Round 2
// 281.009 us; speedup vs baseline: 1.6873x; 1.6873x over previous
//
#include <hip/hip_runtime.h>
#include <hip/hip_bf16.h>
#include <stdint.h>

typedef __attribute__((ext_vector_type(8))) __bf16 bf16x8;
typedef __attribute__((ext_vector_type(4))) float f32x4;
typedef unsigned short u16;

#define MFMA16(a, b, c) __builtin_amdgcn_mfma_f32_16x16x32_bf16((a), (b), (c), 0, 0, 0)

__device__ __forceinline__ u16 f32_to_bf16_rne(float f) {
  union { float f; uint32_t u; } v; v.f = f;
  uint32_t u = v.u;
  u += 0x7fffu + ((u >> 16) & 1u);
  return (u16)(u >> 16);
}

__device__ __forceinline__ void gl_lds16(const void* g, void* l) {
  __builtin_amdgcn_global_load_lds(
      (const __attribute__((address_space(1))) void*)(uintptr_t)g,
      (__attribute__((address_space(3))) void*)(uintptr_t)l,
      16, 0, 0);
}

__device__ __forceinline__ float fast_exp2(float x) {
#if __has_builtin(__builtin_amdgcn_exp2f)
  return __builtin_amdgcn_exp2f(x);
#else
  return exp2f(x);
#endif
}

__device__ __forceinline__ uint32_t cvt_pk_bf16(float a, float b) {
  uint32_t r;
  asm("v_cvt_pk_bf16_f32 %0, %1, %2" : "=v"(r) : "v"(a), "v"(b));
  return r;
}

// ---------------------------------------------------------------- cast kernel
__global__ void cast_f32_bf16_kernel(const float* __restrict__ in,
                                     u16* __restrict__ out, int n4) {
  int i = blockIdx.x * blockDim.x + threadIdx.x;
  if (i >= n4) return;
  float4 v = reinterpret_cast<const float4*>(in)[i];
  ushort4 o;
  o.x = f32_to_bf16_rne(v.x);
  o.y = f32_to_bf16_rne(v.y);
  o.z = f32_to_bf16_rne(v.z);
  o.w = f32_to_bf16_rne(v.w);
  reinterpret_cast<ushort4*>(out)[i] = o;
}

// ---------------------------------------------------------------- GEMM (B^T)
// C[m,n] = sum_k A[m,k]*Bt[n,k]. 128x128 tile, BK=32, 4 waves (2x2), 4x4 frags.
// LDS rows are 64B = 4x16B chunks, XOR-swizzled: chunk' = chunk ^ ((row^(row>>2))&3).
// gl_lds dest stays linear; the global SOURCE is inverse-swizzled (same involution).
template <int FINAL>
__global__ __launch_bounds__(256, 2) void gemm_bt_kernel(
    const u16* __restrict__ A, const u16* __restrict__ Bt,
    void* __restrict__ Cout, const float* __restrict__ bias, int M, int N, int K) {
  __shared__ __attribute__((aligned(16))) u16 As[128 * 32];
  __shared__ __attribute__((aligned(16))) u16 Bs[128 * 32];
  const int tid = threadIdx.x;
  const int lane = tid & 63;
  const int wid = tid >> 6;
  const int wr = wid >> 1, wc = wid & 1;
  const int m0 = blockIdx.y * 128, n0 = blockIdx.x * 128;

  f32x4 acc[4][4] = {};

  // staging lane map: chunk = 16 rows x 4x16B; r=lane>>2 (row in chunk), cc=lane&3
  const int sr = lane >> 2;
  const int scc = lane & 3;
  const int sh = (sr ^ (sr >> 2)) & 3;
  const int sc = ((scc ^ sh) << 3);  // pre-swizzled source col (shorts)
  // read lane map
  const int rl = lane & 15;
  const int rh = (rl ^ (rl >> 2)) & 3;
  const int cpr = (((lane >> 4) ^ rh) << 4);  // swizzled byte chunk offset

  for (int k0 = 0; k0 < K; k0 += 32) {
    __syncthreads();
#pragma unroll
    for (int i = 0; i < 2; ++i) {
      const int c = wid * 2 + i;
      const int row = c * 16 + sr;
      gl_lds16(A + (size_t)(m0 + row) * K + k0 + sc, (char*)As + c * 1024);
      gl_lds16(Bt + (size_t)(n0 + row) * K + k0 + sc, (char*)Bs + c * 1024);
    }
    __syncthreads();

    bf16x8 af[4], bf[4];
#pragma unroll
    for (int mi = 0; mi < 4; ++mi)
      af[mi] = *(const bf16x8*)((const char*)As + (wr * 64 + mi * 16 + rl) * 64 + cpr);
#pragma unroll
    for (int ni = 0; ni < 4; ++ni)
      bf[ni] = *(const bf16x8*)((const char*)Bs + (wc * 64 + ni * 16 + rl) * 64 + cpr);
    __builtin_amdgcn_s_setprio(1);
#pragma unroll
    for (int mi = 0; mi < 4; ++mi)
#pragma unroll
      for (int ni = 0; ni < 4; ++ni)
        acc[mi][ni] = MFMA16(af[mi], bf[ni], acc[mi][ni]);
    __builtin_amdgcn_s_setprio(0);
  }

#pragma unroll
  for (int mi = 0; mi < 4; ++mi) {
#pragma unroll
    for (int ni = 0; ni < 4; ++ni) {
      const int row = m0 + wr * 64 + mi * 16 + ((lane >> 4) << 2);
      const int col = n0 + wc * 64 + ni * 16 + (lane & 15);
#pragma unroll
      for (int j = 0; j < 4; ++j) {
        if (FINAL) {
          reinterpret_cast<float*>(Cout)[(size_t)(row + j) * N + col] =
              acc[mi][ni][j] + bias[col];
        } else {
          reinterpret_cast<u16*>(Cout)[(size_t)(row + j) * N + col] =
              f32_to_bf16_rne(acc[mi][ni][j]);
        }
      }
    }
  }
}

// ---------------------------------------------------------------- attention
// scores[t,s] = (k_t . q_s)/8, causal s<=t, softmax over s, O = P @ V.
// Block = one (b,h) and t-tile PAIR {p, 15-p} (128-row tiles) -> uniform 34 s-tiles.
// 4 waves x 32 rows (mi=2). s-tiles of 64. Pipelined: Qs/Vt double-buffered,
// next-tile staging issued before QK, one barrier per s-tile.
// All LDS tiles have 128B rows, XOR-swizzled chunk' = chunk ^ (row&7).
#define SCL 0.18033688011f  /* 0.125 * log2(e) */
#define NEG (-1e30f)
#define THR_RAW 44.0f       /* = 8 / SCL approx, exp2 arg bound ~8 */

__global__ __launch_bounds__(256, 2) void attn_kernel(
    const u16* __restrict__ Kb, const u16* __restrict__ Qb,
    const u16* __restrict__ Vb, u16* __restrict__ Ob) {
  __shared__ __attribute__((aligned(16))) u16 Ks[128 * 64];
  __shared__ __attribute__((aligned(16))) u16 Qs2[2][64 * 64];
  __shared__ __attribute__((aligned(16))) u16 Vt2[2][64 * 64];
  __shared__ __attribute__((aligned(16))) u16 Ps[128 * 64];

  const int tid = threadIdx.x;
  const int lane = tid & 63;
  const int w = tid >> 6;

  // XCD-grouped decode: 512 blocks; same (b,h) lands on one XCD.
  const int flat = blockIdx.x;
  const int virt = (flat & 7) * 64 + (flat >> 3);
  const int bh = virt >> 3;
  const int pairid = virt & 7;
  const int b = bh >> 4, h = bh & 15;

  const size_t base = (size_t)b * 2048;
  const u16* Kh = Kb + base * 1024 + h * 64;
  const u16* Qh = Qb + base * 1024 + h * 64;
  const u16* Vh = Vb + base * 1024 + h * 64;
  u16* Oh = Ob + base * 1024 + h * 64;

  // staging lane map (1KB chunk = 8 rows x 8x16B): r=lane>>3, c=lane&7
  const int str = lane >> 3;
  const int stc = lane & 7;
  const int ssc = ((stc ^ str) << 3);  // inverse-swizzled source col (shorts)
  const int rl = lane & 15;
  const int G = lane >> 4;

#pragma unroll 1
  for (int pass = 0; pass < 2; ++pass) {
    const int ttile = pass ? (15 - pairid) : pairid;
    const int t0 = ttile * 128;
    const int nst = 2 * ttile + 2;

    // ---- prologue: stage K tile + Q0 + V0
#pragma unroll
    for (int i = 0; i < 4; ++i) {
      const int ch = w * 4 + i;
      const int row = ch * 8 + str;
      gl_lds16(Kh + (size_t)(t0 + row) * 1024 + ssc, (char*)Ks + ch * 1024);
    }
#pragma unroll
    for (int i = 0; i < 2; ++i) {
      const int ch = w * 2 + i;
      const int row = ch * 8 + str;
      gl_lds16(Qh + (size_t)row * 1024 + ssc, (char*)Qs2[0] + ch * 1024);
    }
    {
      uint4 vr0[2];
#pragma unroll
      for (int it = 0; it < 2; ++it) {
        const int idx = it * 256 + tid;
        const int g = idx & 7, srow = idx >> 3;
        vr0[it] = *reinterpret_cast<const uint4*>(Vh + (size_t)srow * 1024 + g * 8);
      }
#pragma unroll
      for (int it = 0; it < 2; ++it) {
        const int idx = it * 256 + tid;
        const int g = idx & 7, srow = idx >> 3;
        const u16* pv = (const u16*)&vr0[it];
        char* buf = (char*)Vt2[0];
#pragma unroll
        for (int u = 0; u < 8; ++u) {
          const int ue = (u + g) & 7;
          const int d = g * 8 + ue;
          *(u16*)(buf + d * 128 + ((((srow >> 3) ^ ue)) << 4) + ((srow & 7) << 1)) = pv[ue];
        }
      }
    }
    __syncthreads();

    f32x4 o_acc[2][4] = {};
    float m_run[2][4], l_run[2][4];
#pragma unroll
    for (int mi = 0; mi < 2; ++mi)
#pragma unroll
      for (int j = 0; j < 4; ++j) { m_run[mi][j] = NEG; l_run[mi][j] = 0.f; }

#pragma unroll 1
    for (int st = 0; st < nst; ++st) {
      const int cur = st & 1;
      const int s0 = st * 64;
      const bool pref = (st + 1 < nst);
      uint4 vr[2];
      if (pref) {
#pragma unroll
        for (int i = 0; i < 2; ++i) {
          const int ch = w * 2 + i;
          const int row = ch * 8 + str;
          gl_lds16(Qh + (size_t)(s0 + 64 + row) * 1024 + ssc,
                   (char*)Qs2[cur ^ 1] + ch * 1024);
        }
#pragma unroll
        for (int it = 0; it < 2; ++it) {
          const int idx = it * 256 + tid;
          const int g = idx & 7, srow = idx >> 3;
          vr[it] = *reinterpret_cast<const uint4*>(
              Vh + (size_t)(s0 + 64 + srow) * 1024 + g * 8);
        }
      }

      // ---- QK^T
      f32x4 s_acc[2][4] = {};
      {
        const char* kb = (const char*)Ks;
        const char* qb = (const char*)Qs2[cur];
        __builtin_amdgcn_s_setprio(1);
#pragma unroll
        for (int kk = 0; kk < 2; ++kk) {
          const int cpr = ((kk * 4 + G) ^ (lane & 7)) << 4;
          bf16x8 af[2], bq[4];
#pragma unroll
          for (int mi = 0; mi < 2; ++mi)
            af[mi] = *(const bf16x8*)(kb + (w * 32 + mi * 16 + rl) * 128 + cpr);
#pragma unroll
          for (int ni = 0; ni < 4; ++ni)
            bq[ni] = *(const bf16x8*)(qb + (ni * 16 + rl) * 128 + cpr);
#pragma unroll
          for (int mi = 0; mi < 2; ++mi)
#pragma unroll
            for (int ni = 0; ni < 4; ++ni)
              s_acc[mi][ni] = MFMA16(af[mi], bq[ni], s_acc[mi][ni]);
        }
        __builtin_amdgcn_s_setprio(0);
      }

      // ---- causal mask (only the 2 diagonal-adjacent tiles need it)
      if (st >= nst - 2) {
        const int colb = s0 + rl;
        const int rowb = t0 + w * 32 + (G << 2);
#pragma unroll
        for (int mi = 0; mi < 2; ++mi)
#pragma unroll
          for (int ni = 0; ni < 4; ++ni) {
            const int s = colb + ni * 16;
#pragma unroll
            for (int j = 0; j < 4; ++j)
              if (s > rowb + mi * 16 + j) s_acc[mi][ni][j] = NEG;
          }
      }

      // ---- online softmax (raw units; exp2 with folded scale; defer-max)
      float tm[2][4];
      bool need = false;
#pragma unroll
      for (int mi = 0; mi < 2; ++mi)
#pragma unroll
        for (int j = 0; j < 4; ++j) {
          float t = fmaxf(fmaxf(s_acc[mi][0][j], s_acc[mi][1][j]),
                          fmaxf(s_acc[mi][2][j], s_acc[mi][3][j]));
          t = fmaxf(t, __shfl_xor(t, 1));
          t = fmaxf(t, __shfl_xor(t, 2));
          t = fmaxf(t, __shfl_xor(t, 4));
          t = fmaxf(t, __shfl_xor(t, 8));
          tm[mi][j] = t;
          need = need || (t > m_run[mi][j] + THR_RAW);
        }
      if (__any(need)) {
#pragma unroll
        for (int mi = 0; mi < 2; ++mi)
#pragma unroll
          for (int j = 0; j < 4; ++j) {
            const float nm = fmaxf(m_run[mi][j], tm[mi][j]);
            const float alpha = fast_exp2((m_run[mi][j] - nm) * SCL);
            m_run[mi][j] = nm;
            l_run[mi][j] *= alpha;
#pragma unroll
            for (int db = 0; db < 4; ++db) o_acc[mi][db][j] *= alpha;
          }
      }
      {
        const int cb = (lane >> 3) & 1;
#pragma unroll
        for (int mi = 0; mi < 2; ++mi)
#pragma unroll
          for (int j = 0; j < 4; ++j) {
            const float mc = m_run[mi][j] * SCL;
            const float p0 = fast_exp2(__builtin_fmaf(s_acc[mi][0][j], SCL, -mc));
            const float p1 = fast_exp2(__builtin_fmaf(s_acc[mi][1][j], SCL, -mc));
            const float p2 = fast_exp2(__builtin_fmaf(s_acc[mi][2][j], SCL, -mc));
            const float p3 = fast_exp2(__builtin_fmaf(s_acc[mi][3][j], SCL, -mc));
            float rs = (p0 + p1) + (p2 + p3);
            rs += __shfl_xor(rs, 1);
            rs += __shfl_xor(rs, 2);
            rs += __shfl_xor(rs, 4);
            rs += __shfl_xor(rs, 8);
            l_run[mi][j] += rs;
            const uint32_t u01 = cvt_pk_bf16(p0, p1);
            const uint32_t u23 = cvt_pk_bf16(p2, p3);
            const int row = w * 32 + mi * 16 + (G << 2) + j;
            const int r7 = row & 7;
            char* prow = (char*)Ps + row * 128 + ((lane & 7) << 1);
            *(u16*)(prow + (((0 + cb) ^ r7) << 4)) = (u16)u01;
            *(u16*)(prow + (((2 + cb) ^ r7) << 4)) = (u16)(u01 >> 16);
            *(u16*)(prow + (((4 + cb) ^ r7) << 4)) = (u16)u23;
            *(u16*)(prow + (((6 + cb) ^ r7) << 4)) = (u16)(u23 >> 16);
          }
      }

      // ---- write NEXT V tile into the other buffer (waits its global loads)
      if (pref) {
#pragma unroll
        for (int it = 0; it < 2; ++it) {
          const int idx = it * 256 + tid;
          const int g = idx & 7, srow = idx >> 3;
          const u16* pv = (const u16*)&vr[it];
          char* buf = (char*)Vt2[cur ^ 1];
#pragma unroll
          for (int u = 0; u < 8; ++u) {
            const int ue = (u + g) & 7;
            const int d = g * 8 + ue;
            *(u16*)(buf + d * 128 + (((srow >> 3) ^ ue) << 4) + ((srow & 7) << 1)) = pv[ue];
          }
        }
      }

      // ---- O += P @ V
      {
        const char* pb = (const char*)Ps;
        const char* vb = (const char*)Vt2[cur];
        __builtin_amdgcn_s_setprio(1);
#pragma unroll
        for (int kk = 0; kk < 2; ++kk) {
          const int cpr = ((kk * 4 + G) ^ (lane & 7)) << 4;
          bf16x8 pa[2], bv[4];
#pragma unroll
          for (int mi = 0; mi < 2; ++mi)
            pa[mi] = *(const bf16x8*)(pb + (w * 32 + mi * 16 + rl) * 128 + cpr);
#pragma unroll
          for (int db = 0; db < 4; ++db)
            bv[db] = *(const bf16x8*)(vb + (db * 16 + rl) * 128 + cpr);
#pragma unroll
          for (int mi = 0; mi < 2; ++mi)
#pragma unroll
            for (int db = 0; db < 4; ++db)
              o_acc[mi][db] = MFMA16(pa[mi], bv[db], o_acc[mi][db]);
        }
        __builtin_amdgcn_s_setprio(0);
      }
      __syncthreads();
    }

    // ---- epilogue: normalize, store
#pragma unroll
    for (int mi = 0; mi < 2; ++mi) {
      float inv[4];
#pragma unroll
      for (int j = 0; j < 4; ++j) inv[j] = 1.0f / l_run[mi][j];
      const int trow = t0 + w * 32 + mi * 16 + (G << 2);
#pragma unroll
      for (int db = 0; db < 4; ++db) {
        const int col = db * 16 + rl;
#pragma unroll
        for (int j = 0; j < 4; ++j)
          Oh[(size_t)(trow + j) * 1024 + col] = f32_to_bf16_rne(o_acc[mi][db][j] * inv[j]);
      }
    }
  }
}

// ---------------------------------------------------------------- launch
extern "C" void kernel_launch(void* const* d_in, const int* in_sizes, int n_in,
                              void* d_out, int out_size, void* d_ws, size_t ws_size,
                              hipStream_t stream) {
  (void)in_sizes; (void)n_in; (void)out_size; (void)ws_size;
  const float* x  = (const float*)d_in[0];
  const float* Wk = (const float*)d_in[1];
  const float* Wq = (const float*)d_in[2];
  const float* Wv = (const float*)d_in[3];
  const float* Wo = (const float*)d_in[4];
  const float* bo = (const float*)d_in[5];
  float* out = (float*)d_out;

  const int BT = 8192, E = 1024;

  char* ws = (char*)d_ws;
  u16* xb  = (u16*)(ws);                        // 16MB, reused as attn-out
  u16* Kb  = (u16*)(ws + ((size_t)16 << 20));   // 16MB
  u16* Qb  = (u16*)(ws + ((size_t)32 << 20));   // 16MB
  u16* Vb  = (u16*)(ws + ((size_t)48 << 20));   // 16MB
  u16* Wkb = (u16*)(ws + ((size_t)64 << 20));   // 2MB
  u16* Wqb = (u16*)(ws + ((size_t)66 << 20));   // 2MB
  u16* Wvb = (u16*)(ws + ((size_t)68 << 20));   // 2MB
  u16* Wob = (u16*)(ws + ((size_t)70 << 20));   // 2MB -> 72MB total

  cast_f32_bf16_kernel<<<dim3(BT * E / 4 / 256), 256, 0, stream>>>(x, xb, BT * E / 4);
  cast_f32_bf16_kernel<<<dim3(E * E / 4 / 256), 256, 0, stream>>>(Wk, Wkb, E * E / 4);
  cast_f32_bf16_kernel<<<dim3(E * E / 4 / 256), 256, 0, stream>>>(Wq, Wqb, E * E / 4);
  cast_f32_bf16_kernel<<<dim3(E * E / 4 / 256), 256, 0, stream>>>(Wv, Wvb, E * E / 4);
  cast_f32_bf16_kernel<<<dim3(E * E / 4 / 256), 256, 0, stream>>>(Wo, Wob, E * E / 4);

  dim3 gg(E / 128, BT / 128);
  gemm_bt_kernel<0><<<gg, 256, 0, stream>>>(xb, Wkb, Kb, nullptr, BT, E, E);
  gemm_bt_kernel<0><<<gg, 256, 0, stream>>>(xb, Wqb, Qb, nullptr, BT, E, E);
  gemm_bt_kernel<0><<<gg, 256, 0, stream>>>(xb, Wvb, Vb, nullptr, BT, E, E);

  attn_kernel<<<dim3(512), 256, 0, stream>>>(Kb, Qb, Vb, xb);

  gemm_bt_kernel<1><<<gg, 256, 0, stream>>>(xb, Wob, out, bo, BT, E, E);
}

// Round 3
// 193.069 us; speedup vs baseline: 2.4559x; 1.4555x over previous
//
#include <hip/hip_runtime.h>
#include <hip/hip_bf16.h>
#include <stdint.h>

typedef __attribute__((ext_vector_type(8))) __bf16 bf16x8;
typedef __attribute__((ext_vector_type(4))) float f32x4;
typedef __attribute__((ext_vector_type(16))) float f32x16;
typedef unsigned short u16;

#define MFMA16(a, b, c) __builtin_amdgcn_mfma_f32_16x16x32_bf16((a), (b), (c), 0, 0, 0)
#define MFMA32(a, b, c) __builtin_amdgcn_mfma_f32_32x32x16_bf16((a), (b), (c), 0, 0, 0)

__device__ __forceinline__ u16 f32_to_bf16_rne(float f) {
  union { float f; uint32_t u; } v; v.f = f;
  uint32_t u = v.u;
  u += 0x7fffu + ((u >> 16) & 1u);
  return (u16)(u >> 16);
}

__device__ __forceinline__ void gl_lds16(const void* g, void* l) {
  __builtin_amdgcn_global_load_lds(
      (const __attribute__((address_space(1))) void*)(uintptr_t)g,
      (__attribute__((address_space(3))) void*)(uintptr_t)l,
      16, 0, 0);
}

__device__ __forceinline__ float fast_exp2(float x) {
#if __has_builtin(__builtin_amdgcn_exp2f)
  return __builtin_amdgcn_exp2f(x);
#else
  return exp2f(x);
#endif
}

__device__ __forceinline__ uint32_t cvt_pk_bf16(float a, float b) {
  uint32_t r;
  asm("v_cvt_pk_bf16_f32 %0, %1, %2" : "=v"(r) : "v"(a), "v"(b));
  return r;
}

// ---------------------------------------------------------------- fused cast
// x (2M float4) -> xb ; Wk/Wq/Wv (256K float4 each) -> wqkv rows 0/1024/2048 ;
// Wo -> wob. Grid covers exactly 3,145,728 float4s.
__global__ void cast_all_kernel(const float* __restrict__ x, const float* __restrict__ Wk,
                                const float* __restrict__ Wq, const float* __restrict__ Wv,
                                const float* __restrict__ Wo, u16* __restrict__ xb,
                                u16* __restrict__ wqkv, u16* __restrict__ wob) {
  const int i = blockIdx.x * 256 + threadIdx.x;
  const float* src; u16* dst; int off;
  if (i < 2097152)      { src = x;  dst = xb;             off = i; }
  else if (i < 2359296) { src = Wk; dst = wqkv;           off = i - 2097152; }
  else if (i < 2621440) { src = Wq; dst = wqkv + 1048576; off = i - 2359296; }
  else if (i < 2883584) { src = Wv; dst = wqkv + 2097152; off = i - 2621440; }
  else                  { src = Wo; dst = wob;            off = i - 2883584; }
  float4 v = reinterpret_cast<const float4*>(src)[off];
  ushort4 o;
  o.x = f32_to_bf16_rne(v.x);
  o.y = f32_to_bf16_rne(v.y);
  o.z = f32_to_bf16_rne(v.z);
  o.w = f32_to_bf16_rne(v.w);
  reinterpret_cast<ushort4*>(dst)[off] = o;
}

// ---------------------------------------------------------------- GEMM (B^T)
// C[m,n] = sum_k A[m,k]*Bt[n,k]. 128x128 tile, BK=32, 4 waves (2x2), 4x4 frags.
// LDS rows are 64B = 4x16B chunks, XOR-swizzled: chunk' = chunk ^ ((row^(row>>2))&3).
template <int FINAL>
__global__ __launch_bounds__(256, 2) void gemm_bt_kernel(
    const u16* __restrict__ A, const u16* __restrict__ Bt,
    void* __restrict__ Cout, const float* __restrict__ bias, int M, int N, int K) {
  __shared__ __attribute__((aligned(16))) u16 As[128 * 32];
  __shared__ __attribute__((aligned(16))) u16 Bs[128 * 32];
  const int tid = threadIdx.x;
  const int lane = tid & 63;
  const int wid = tid >> 6;
  const int wr = wid >> 1, wc = wid & 1;
  const int m0 = blockIdx.y * 128, n0 = blockIdx.x * 128;

  f32x4 acc[4][4] = {};

  const int sr = lane >> 2;
  const int scc = lane & 3;
  const int sh = (sr ^ (sr >> 2)) & 3;
  const int sc = ((scc ^ sh) << 3);
  const int rl = lane & 15;
  const int rh = (rl ^ (rl >> 2)) & 3;
  const int cpr = (((lane >> 4) ^ rh) << 4);

  for (int k0 = 0; k0 < K; k0 += 32) {
    __syncthreads();
#pragma unroll
    for (int i = 0; i < 2; ++i) {
      const int c = wid * 2 + i;
      const int row = c * 16 + sr;
      gl_lds16(A + (size_t)(m0 + row) * K + k0 + sc, (char*)As + c * 1024);
      gl_lds16(Bt + (size_t)(n0 + row) * K + k0 + sc, (char*)Bs + c * 1024);
    }
    __syncthreads();

    bf16x8 af[4], bf[4];
#pragma unroll
    for (int mi = 0; mi < 4; ++mi)
      af[mi] = *(const bf16x8*)((const char*)As + (wr * 64 + mi * 16 + rl) * 64 + cpr);
#pragma unroll
    for (int ni = 0; ni < 4; ++ni)
      bf[ni] = *(const bf16x8*)((const char*)Bs + (wc * 64 + ni * 16 + rl) * 64 + cpr);
    __builtin_amdgcn_s_setprio(1);
#pragma unroll
    for (int mi = 0; mi < 4; ++mi)
#pragma unroll
      for (int ni = 0; ni < 4; ++ni)
        acc[mi][ni] = MFMA16(af[mi], bf[ni], acc[mi][ni]);
    __builtin_amdgcn_s_setprio(0);
  }

#pragma unroll
  for (int mi = 0; mi < 4; ++mi) {
#pragma unroll
    for (int ni = 0; ni < 4; ++ni) {
      const int row = m0 + wr * 64 + mi * 16 + ((lane >> 4) << 2);
      const int col = n0 + wc * 64 + ni * 16 + (lane & 15);
#pragma unroll
      for (int j = 0; j < 4; ++j) {
        if (FINAL) {
          reinterpret_cast<float*>(Cout)[(size_t)(row + j) * N + col] =
              acc[mi][ni][j] + bias[col];
        } else {
          reinterpret_cast<u16*>(Cout)[(size_t)(row + j) * N + col] =
              f32_to_bf16_rne(acc[mi][ni][j]);
        }
      }
    }
  }
}

// ---------------------------------------------------------------- attention
// scores[t,s] = (k_t . q_s)/8, causal, softmax over s, O = P @ V.
// Block = (b, head, ttile). 4 waves x 32 t-rows. s-tiles of 64.
// QK computed TRANSPOSED via 32x32x16 mfma: C'[s,t] -> lane owns t = lane&31,
// softmax lane-local (+1 xor32 shuffle). P stays in registers: cvt_pk + xor32
// shuffles assemble PV's A-fragment directly. K B-frags hoisted to regs once.
// LDS: granule(16B)-column-major layouts -> all ds_read_b128 conflict-free;
// gl_lds dest linear, transpose folded into per-lane GLOBAL source address.
#define KQVS 3072
#define SCL 0.18033688011f /* 0.125 * log2(e) */
#define NEG (-1e30f)
#define THR_RAW 44.0f

__device__ __forceinline__ void v_load(uint4* vr, const u16* __restrict__ Vsrc,
                                       int s0, int tid) {
#pragma unroll
  for (int it = 0; it < 2; ++it) {
    const int idx = it * 256 + tid;
    const int g = idx & 7, srow = idx >> 3;
    vr[it] = *reinterpret_cast<const uint4*>(Vsrc + (size_t)(s0 + srow) * KQVS + g * 8);
  }
}

// Vt granule layout: granule (cc = s>>3, d) at u16 offset (cc*64+d)*8, slot s&7.
__device__ __forceinline__ void vt_write(u16* buf, const uint4* vr, int tid) {
#pragma unroll
  for (int it = 0; it < 2; ++it) {
    const int idx = it * 256 + tid;
    const int g = idx & 7, srow = idx >> 3;
    const u16* pv = reinterpret_cast<const u16*>(&vr[it]);
#pragma unroll
    for (int u = 0; u < 8; ++u) {
      const int ue = (u + g) & 7;  // per-lane rotation: conflict-free banks
      const int d = g * 8 + ue;
      buf[((srow >> 3) * 64 + d) * 8 + (srow & 7)] = pv[ue];
    }
  }
}

__global__ __launch_bounds__(256, 3) void attn_kernel(
    const u16* __restrict__ KQV, u16* __restrict__ Ob) {
  __shared__ __attribute__((aligned(16))) u16 Ks[8192];      // (cc*128+trow)*8
  __shared__ __attribute__((aligned(16))) u16 Qs2[2][4096];  // (cc*64+srow)*8
  __shared__ __attribute__((aligned(16))) u16 Vt2[2][4096];  // (cc*64+d)*8

  const int tid = threadIdx.x;
  const int lane = tid & 63;
  const int wv = tid >> 6;
  const int l31 = lane & 31;
  const int hh = lane >> 5;
  const bool lolane = (hh == 0);

  // big-tiles-first (LPT) + XCD-grouped (b,h)
  const int idx = blockIdx.x;
  const int ttile = 15 - (idx >> 6);
  const int bhpos = idx & 63;
  const int bh = (bhpos & 7) * 8 + (bhpos >> 3);
  const int b = bh >> 4, head = bh & 15;

  const size_t rbase = (size_t)b * 2048;
  const u16* Kh = KQV + rbase * KQVS + head * 64;
  const u16* Qh = Kh + 1024;
  const u16* Vh = Kh + 2048;
  u16* Oh = Ob + rbase * 1024 + head * 64;

  const int t0 = ttile * 128;
  const int nst = 2 * ttile + 2;
  const int t0w = t0 + wv * 32;
  const int tl = t0w + l31;  // this lane's t-row (P-domain)
  const int rb4 = 4 * hh;

  // ---- prologue: stage K (16 chunks), Q0 (8), V0 (reg->LDS transpose)
#pragma unroll
  for (int i = 0; i < 4; ++i) {
    const int ch = wv * 4 + i;
    const int cc = ch >> 1;
    const int trow = (ch & 1) * 64 + lane;
    gl_lds16(Kh + (size_t)(t0 + trow) * KQVS + cc * 8, (char*)Ks + ch * 1024);
  }
#pragma unroll
  for (int i = 0; i < 2; ++i) {
    const int ch = wv * 2 + i;
    gl_lds16(Qh + (size_t)lane * KQVS + ch * 8, (char*)Qs2[0] + ch * 1024);
  }
  {
    uint4 vr0[2];
    v_load(vr0, Vh, 0, tid);
    vt_write(Vt2[0], vr0, tid);
  }
  __syncthreads();

  // hoisted K fragments: B[k=d][col=t], reused for every s-tile
  bf16x8 kf[4];
#pragma unroll
  for (int kk = 0; kk < 4; ++kk)
    kf[kk] = *(const bf16x8*)(Ks + ((kk * 2 + hh) * 128 + wv * 32 + l31) * 8);

  f32x16 oa0 = {}, oa1 = {};
  float m_run = NEG, l_run = 0.f;

#pragma unroll 1
  for (int st = 0; st < nst; ++st) {
    const int cur = st & 1;
    const int s0 = st * 64;
    const bool pref = (st + 1 < nst);
    uint4 vr[2];
    if (pref) {
#pragma unroll
      for (int i = 0; i < 2; ++i) {
        const int ch = wv * 2 + i;
        gl_lds16(Qh + (size_t)(s0 + 64 + lane) * KQVS + ch * 8,
                 (char*)Qs2[cur ^ 1] + ch * 1024);
      }
      v_load(vr, Vh, s0 + 64, tid);
    }

    const bool active = (s0 <= t0w + 31);
    f32x16 sa0 = {}, sa1 = {};
    if (active) {
      // ---- QK^T (transposed): C'[s,t], A = Q rows, B = hoisted K
      const u16* qb = Qs2[cur];
      __builtin_amdgcn_s_setprio(1);
#pragma unroll
      for (int kk = 0; kk < 4; ++kk) {
        bf16x8 a0 = *(const bf16x8*)(qb + ((kk * 2 + hh) * 64 + l31) * 8);
        bf16x8 a1 = *(const bf16x8*)(qb + ((kk * 2 + hh) * 64 + 32 + l31) * 8);
        sa0 = MFMA32(a0, kf[kk], sa0);
        sa1 = MFMA32(a1, kf[kk], sa1);
      }
      __builtin_amdgcn_s_setprio(0);

      // ---- causal mask (s > t): only near-diagonal tiles
      if (s0 + 63 > t0w) {
#pragma unroll
        for (int r = 0; r < 16; ++r) {
          const int rowloc = (r & 3) + 8 * (r >> 2) + rb4;
          if (s0 + rowloc > tl) sa0[r] = NEG;
          if (s0 + 32 + rowloc > tl) sa1[r] = NEG;
        }
      }

      // ---- row max (lane-local tree + partner)
      float mA = fmaxf(fmaxf(fmaxf(sa0[0], sa0[1]), fmaxf(sa0[2], sa0[3])),
                       fmaxf(fmaxf(sa0[4], sa0[5]), fmaxf(sa0[6], sa0[7])));
      float mB = fmaxf(fmaxf(fmaxf(sa0[8], sa0[9]), fmaxf(sa0[10], sa0[11])),
                       fmaxf(fmaxf(sa0[12], sa0[13]), fmaxf(sa0[14], sa0[15])));
      float mC = fmaxf(fmaxf(fmaxf(sa1[0], sa1[1]), fmaxf(sa1[2], sa1[3])),
                       fmaxf(fmaxf(sa1[4], sa1[5]), fmaxf(sa1[6], sa1[7])));
      float mD = fmaxf(fmaxf(fmaxf(sa1[8], sa1[9]), fmaxf(sa1[10], sa1[11])),
                       fmaxf(fmaxf(sa1[12], sa1[13]), fmaxf(sa1[14], sa1[15])));
      float tm = fmaxf(fmaxf(mA, mB), fmaxf(mC, mD));
      tm = fmaxf(tm, __shfl_xor(tm, 32));

      const bool need = tm > m_run + THR_RAW;  // defer-max
      if (__any(need)) {
        const float nm = fmaxf(m_run, tm);
        const float alpha = fast_exp2((m_run - nm) * SCL);
        m_run = nm;
        l_run *= alpha;
#pragma unroll
        for (int r = 0; r < 16; ++r) {
          const float ar = __shfl(alpha, (r & 3) + 8 * (r >> 2) + rb4);
          oa0[r] *= ar;
          oa1[r] *= ar;
        }
      }

      // ---- P = exp2((S - m)*SCL), row-sum
      const float mc = m_run * SCL;
#pragma unroll
      for (int r = 0; r < 16; ++r) {
        sa0[r] = fast_exp2(__builtin_fmaf(sa0[r], SCL, -mc));
        sa1[r] = fast_exp2(__builtin_fmaf(sa1[r], SCL, -mc));
      }
      float rsA = ((sa0[0] + sa0[1]) + (sa0[2] + sa0[3])) +
                  ((sa0[4] + sa0[5]) + (sa0[6] + sa0[7]));
      float rsB = ((sa0[8] + sa0[9]) + (sa0[10] + sa0[11])) +
                  ((sa0[12] + sa0[13]) + (sa0[14] + sa0[15]));
      float rsC = ((sa1[0] + sa1[1]) + (sa1[2] + sa1[3])) +
                  ((sa1[4] + sa1[5]) + (sa1[6] + sa1[7]));
      float rsD = ((sa1[8] + sa1[9]) + (sa1[10] + sa1[11])) +
                  ((sa1[12] + sa1[13]) + (sa1[14] + sa1[15]));
      float rs = (rsA + rsB) + (rsC + rsD);
      rs += __shfl_xor(rs, 32);
      l_run += rs;
    }

    // ---- write NEXT V tile (loads were issued before QK)
    if (pref) vt_write(Vt2[cur ^ 1], vr, tid);

    // ---- O += P @ V : A-frag assembled in-register from P
    if (active) {
      const u16* vb = Vt2[cur];
      __builtin_amdgcn_s_setprio(1);
#define PV_WINDOW(P, r0, w)                                                   \
  {                                                                           \
    uint32_t dA = cvt_pk_bf16(P[r0 + 0], P[r0 + 1]);                          \
    uint32_t dB = cvt_pk_bf16(P[r0 + 2], P[r0 + 3]);                          \
    uint32_t dC = cvt_pk_bf16(P[r0 + 4], P[r0 + 5]);                          \
    uint32_t dD = cvt_pk_bf16(P[r0 + 6], P[r0 + 7]);                          \
    uint32_t sdA = (uint32_t)__shfl_xor((int)dA, 32);                         \
    uint32_t sdB = (uint32_t)__shfl_xor((int)dB, 32);                         \
    uint32_t sdC = (uint32_t)__shfl_xor((int)dC, 32);                         \
    uint32_t sdD = (uint32_t)__shfl_xor((int)dD, 32);                         \
    union { uint32_t u[4]; bf16x8 v; } af;                                    \
    af.u[0] = lolane ? dA : sdC;                                              \
    af.u[1] = lolane ? dB : sdD;                                              \
    af.u[2] = lolane ? sdA : dC;                                              \
    af.u[3] = lolane ? sdB : dD;                                              \
    bf16x8 bv0 = *(const bf16x8*)(vb + ((2 * (w) + hh) * 64 + l31) * 8);      \
    bf16x8 bv1 = *(const bf16x8*)(vb + ((2 * (w) + hh) * 64 + 32 + l31) * 8); \
    oa0 = MFMA32(af.v, bv0, oa0);                                             \
    oa1 = MFMA32(af.v, bv1, oa1);                                             \
  }
      PV_WINDOW(sa0, 0, 0)
      PV_WINDOW(sa0, 8, 1)
      PV_WINDOW(sa1, 0, 2)
      PV_WINDOW(sa1, 8, 3)
#undef PV_WINDOW
      __builtin_amdgcn_s_setprio(0);
    }
    __syncthreads();
  }

  // ---- epilogue: normalize (1/l broadcast P-domain -> O-domain), store
  {
    const float inv = 1.0f / l_run;
#pragma unroll
    for (int r = 0; r < 16; ++r) {
      const int rowloc = (r & 3) + 8 * (r >> 2) + rb4;
      const float ir = __shfl(inv, rowloc);
      const int trow = t0w + rowloc;
      Oh[(size_t)trow * 1024 + l31] = f32_to_bf16_rne(oa0[r] * ir);
      Oh[(size_t)trow * 1024 + 32 + l31] = f32_to_bf16_rne(oa1[r] * ir);
    }
  }
}

// ---------------------------------------------------------------- launch
extern "C" void kernel_launch(void* const* d_in, const int* in_sizes, int n_in,
                              void* d_out, int out_size, void* d_ws, size_t ws_size,
                              hipStream_t stream) {
  (void)in_sizes; (void)n_in; (void)out_size; (void)ws_size;
  const float* x  = (const float*)d_in[0];
  const float* Wk = (const float*)d_in[1];
  const float* Wq = (const float*)d_in[2];
  const float* Wv = (const float*)d_in[3];
  const float* Wo = (const float*)d_in[4];
  const float* bo = (const float*)d_in[5];
  float* out = (float*)d_out;

  char* ws = (char*)d_ws;
  u16* xb   = (u16*)(ws);                       // 16MB (x cast, later attn-out)
  u16* kqv  = (u16*)(ws + ((size_t)16 << 20));  // 48MB [8192 x 3072] K|Q|V
  u16* wqkv = (u16*)(ws + ((size_t)64 << 20));  // 6MB  [3072 x 1024]
  u16* wob  = (u16*)(ws + ((size_t)70 << 20));  // 2MB -> 72MB total

  cast_all_kernel<<<dim3(12288), 256, 0, stream>>>(x, Wk, Wq, Wv, Wo, xb, wqkv, wob);

  // fused K/Q/V projection: [8192,3072] = [8192,1024] x [3072,1024]^T
  gemm_bt_kernel<0><<<dim3(24, 64), 256, 0, stream>>>(xb, wqkv, kqv, nullptr, 8192, 3072, 1024);

  // attention (writes into xb)
  attn_kernel<<<dim3(1024), 256, 0, stream>>>(kqv, xb);

  // final projection + bias, f32 out
  gemm_bt_kernel<1><<<dim3(8, 64), 256, 0, stream>>>(xb, wob, out, bo, 8192, 1024, 1024);
}